// Round 8
// baseline (43872.546 us; speedup 1.0000x reference)
//
#include <hip/hip_runtime.h>
#include <math.h>

typedef _Float16 h8 __attribute__((ext_vector_type(8)));
typedef float f4 __attribute__((ext_vector_type(4)));
typedef unsigned long long u64;

#define H 1024

// ---- workspace layout (bytes) ----
#define OFF_WRZ0 0ull            // fp16 [2048][1536]
#define OFF_WN0  6291456ull      // fp16 [1024][1536]
#define OFF_WRZ1 9437184ull      // fp16 [2048][2048]
#define OFF_WN1  17825792ull     // fp16 [1024][2048]
#define OFF_H0H  22020096ull     // fp16 [4][64][1024] ring-4
#define OFF_H1H  22544384ull     // fp16 [2][64][1024]
#define OFF_RH0  22806528ull     // fp16 [64][1024]
#define OFF_RH1  22937600ull     // fp16 [64][1024]
#define OFF_H0F  23068672ull     // f32 [64][1024]
#define OFF_H1F  23330816ull     // f32 [64][1024]
#define OFF_Z0F  23592960ull     // f32 [64][1024]
#define OFF_Z1F  23855104ull     // f32 [64][1024]
#define OFF_CNT  24117248ull     // u64 [5 ctr] stride 16 u64 (128B)
#define OFF_XR   24117888ull     // f32 ring [8][64][3072] = 6291456 B
#define ZERO_WORDS 524448        // (24117888 - 22020096)/4

// ---------------- LLC-bypass (agent-scope relaxed) — r2-proven ----------------
__device__ __forceinline__ u64 llc_ld64(const void* p) {
  return __hip_atomic_load((const u64*)p, __ATOMIC_RELAXED, __HIP_MEMORY_SCOPE_AGENT);
}
__device__ __forceinline__ unsigned llc_ld32(const void* p) {
  return __hip_atomic_load((const unsigned*)p, __ATOMIC_RELAXED, __HIP_MEMORY_SCOPE_AGENT);
}
__device__ __forceinline__ float llc_ldf(const float* p) {
  return __uint_as_float(llc_ld32(p));
}
__device__ __forceinline__ void llc_st32(void* p, unsigned v) {
  __hip_atomic_store((unsigned*)p, v, __ATOMIC_RELAXED, __HIP_MEMORY_SCOPE_AGENT);
}
union H16B { _Float16 h; unsigned short u; };

#define MFMA16(a, b, c) __builtin_amdgcn_mfma_f32_16x16x32_f16((a), (b), (c), 0, 0, 0)

// ---------------- prep ----------------
__global__ __launch_bounds__(256) void prep_kernel(
    const float* __restrict__ wrz0f, const float* __restrict__ wn0f,
    const float* __restrict__ wrz1f, const float* __restrict__ wn1f,
    _Float16* __restrict__ wrz0, _Float16* __restrict__ wn0,
    _Float16* __restrict__ wrz1, _Float16* __restrict__ wn1,
    unsigned* __restrict__ zbase) {
  size_t i = (size_t)blockIdx.x * blockDim.x + threadIdx.x;
  size_t stride = (size_t)gridDim.x * blockDim.x;
  for (size_t k = i; k < 2048ull * 1536ull; k += stride) wrz0[k] = (_Float16)wrz0f[k];
  for (size_t k = i; k < 1024ull * 1536ull; k += stride) wn0[k]  = (_Float16)wn0f[k];
  for (size_t k = i; k < 2048ull * 2048ull; k += stride) wrz1[k] = (_Float16)wrz1f[k];
  for (size_t k = i; k < 1024ull * 2048ull; k += stride) wn1[k]  = (_Float16)wn1f[k];
  for (size_t k = i; k < (size_t)ZERO_WORDS; k += stride) zbase[k] = 0u;
}

// ---------------- counters (thread0 poll, vmcnt-drain release) ----------------
__device__ __forceinline__ void wait_ge(u64* c, u64 tgt, int* sdead) {
  if (threadIdx.x == 0 && *sdead == 0) {
    int g = 0;
    while (__hip_atomic_load(c, __ATOMIC_RELAXED, __HIP_MEMORY_SCOPE_AGENT) < tgt) {
      if (++g > (1 << 20)) { *sdead = 1; break; }   // fail loud, never hang
      __builtin_amdgcn_s_sleep(1);
    }
  }
  __syncthreads();
}
__device__ __forceinline__ void signal_add(u64* c) {
  __syncthreads();   // drains all waves' vmcnt: LLC stores visible before bump
  if (threadIdx.x == 0)
    __hip_atomic_fetch_add(c, 1ull, __ATOMIC_RELAXED, __HIP_MEMORY_SCOPE_AGENT);
}

// ---------------- stage 128KB: issue-all bypass loads, 16B swizzled LDS writes ----------------
__device__ __forceinline__ void stage128(const _Float16* __restrict__ src,
                                         char* __restrict__ sA) {
  const int tid = threadIdx.x;
  u64 t0[8], t1[8];
#pragma unroll
  for (int i = 0; i < 8; ++i) {
    int u = tid + (i << 10);                  // 8192 16B units
    t0[i] = llc_ld64(src + ((size_t)u << 3));
    t1[i] = llc_ld64(src + ((size_t)u << 3) + 4);
  }
#pragma unroll
  for (int i = 0; i < 8; ++i) {
    int u = tid + (i << 10);
    int row = u >> 7, q = u & 127;            // 128 16B-units per 2KB row
    unsigned byt = (((unsigned)row << 11) + ((unsigned)q << 4)) ^ (((unsigned)(row & 7)) << 4);
    u64* p = (u64*)(sA + byt);
    p[0] = t0[i]; p[1] = t1[i];
  }
}

// ---------------- GEMM: NT 16-col tiles, full K=1024, A from swizzled LDS ----------------
template<int NT>
__device__ __forceinline__ void gemmNT(const char* __restrict__ sA, int arow,
                                       const _Float16* const* w, int kg8, f4* acc) {
  const unsigned rb = (unsigned)arow << 11;
  const unsigned swz = ((unsigned)(arow & 7)) << 4;
#pragma unroll
  for (int kw = 0; kw < 32; ++kw) {
    int k = kw * 32 + kg8;
    h8 a = *(const h8*)(sA + ((rb + ((unsigned)k << 1)) ^ swz));
#pragma unroll
    for (int c = 0; c < NT; ++c)
      acc[c] = MFMA16(a, *(const h8*)(w[c] + k), acc[c]);
  }
}

// prefetch 4 gate values at (rows, col) — proven fragment mapping
__device__ __forceinline__ void pref4t(float* dst, const float* __restrict__ src,
                                       int colb, int mg, int ldm) {
  int lane = threadIdx.x & 63;
  int col = colb + (lane & 15);
  int r0 = mg * 16 + ((lane >> 4) << 2);
#pragma unroll
  for (int j = 0; j < 4; ++j) dst[j] = llc_ldf(src + (size_t)(r0 + j) * ldm + col);
}

// rz apply: sigmoid; r-blocks -> rh (fp16 pair-packed), z-blocks -> zf
__device__ __forceinline__ void apply_rz2(f4 a, int colb, int mg,
    const float* __restrict__ bias, bool isR, const float* hp, const float* xp,
    _Float16* __restrict__ rh, float* __restrict__ zf) {
  int lane = threadIdx.x & 63;
  int col = colb + (lane & 15);
  int r0 = mg * 16 + ((lane >> 4) << 2);
#pragma unroll
  for (int j = 0; j < 4; ++j) {
    float v = a[j] + bias[col] + (xp ? xp[j] : 0.f);
    float s = 1.f / (1.f + expf(-v));
    int row = r0 + j;
    if (isR) {
      H16B c; c.h = (_Float16)(s * hp[j]);
      unsigned pr = (unsigned)__shfl_xor((int)(unsigned)c.u, 1);
      if (!(lane & 1)) llc_st32(rh + (size_t)row * H + col, (unsigned)c.u | (pr << 16));
    } else {
      llc_st32(zf + (size_t)row * H + (col - 1024), __float_as_uint(s));
    }
  }
}

// n apply: tanh + h update -> hf (f32 master) + hh (fp16 pair-packed)
__device__ __forceinline__ void apply_n2(f4 a, int colb, int mg,
    const float* __restrict__ bias, const float* pz, const float* ph, const float* xp,
    float* __restrict__ hfout, _Float16* __restrict__ hh) {
  int lane = threadIdx.x & 63;
  int col = colb + (lane & 15);
  int r0 = mg * 16 + ((lane >> 4) << 2);
#pragma unroll
  for (int j = 0; j < 4; ++j) {
    int row = r0 + j;
    float v = a[j] + bias[col] + (xp ? xp[j] : 0.f);
    float nn = tanhf(v);
    float o = (1.f - pz[j]) * nn + pz[j] * ph[j];
    llc_st32(hfout + (size_t)row * H + col, __float_as_uint(o));
    H16B c; c.h = (_Float16)o;
    unsigned pr = (unsigned)__shfl_xor((int)(unsigned)c.u, 1);
    if (!(lane & 1)) llc_st32(hh + (size_t)row * H + col, (unsigned)c.u | (pr << 16));
  }
}

// ---------------- persistent GRU ----------------
// blocks 0..15: L0 (rz0+n0, step t); 16..31: A = rz1(s); 32..47: B = n1(s); 48..63: xproj
__global__ __launch_bounds__(1024, 1) void gru_main(const float* __restrict__ x,
    const _Float16* __restrict__ wrz0, const _Float16* __restrict__ wn0,
    const _Float16* __restrict__ wrz1, const _Float16* __restrict__ wn1,
    const float* __restrict__ brz0, const float* __restrict__ bn0,
    const float* __restrict__ brz1, const float* __restrict__ bn1,
    _Float16* __restrict__ h0h, _Float16* __restrict__ h1h,
    _Float16* __restrict__ rh0, _Float16* __restrict__ rh1,
    float* __restrict__ h0f, float* __restrict__ h1f,
    float* __restrict__ z0f, float* __restrict__ z1f,
    float* __restrict__ xring, u64* __restrict__ cnt) {
  __shared__ char sA[131072];
  __shared__ int sdead;
  const int bid = blockIdx.x, tid = threadIdx.x;
  const int lane = tid & 63, wv = tid >> 6;
  const int mg = wv & 3, wsel = wv >> 2;
  const int rsub = lane & 15, kg8 = (lane >> 4) << 3;
  const int arow = mg * 16 + rsub;
  if (tid == 0) sdead = 0;
  __syncthreads();
  u64* c_rz0 = cnt;      u64* c_n0 = cnt + 16;
  u64* c_rz1 = cnt + 32; u64* c_n1 = cnt + 48;
  u64* c_xp  = cnt + 64;
  const f4 fz = f4{0.f, 0.f, 0.f, 0.f};

  if (bid < 16) {
    // ---------- L0: rz0(t) then n0(t) ----------
    const int b = bid;
    const bool isR = b < 8;
    const int colb0 = b * 128 + wsel * 32, colb1 = colb0 + 16;
    const int colbN = b * 64 + wsel * 16;
    const _Float16* wR[2] = { wrz0 + (size_t)(colb0 + rsub) * 1536 + 512,
                              wrz0 + (size_t)(colb1 + rsub) * 1536 + 512 };
    const _Float16* wN[1] = { wn0 + (size_t)(colbN + rsub) * 1536 + 512 };
    for (int t = 0; t < 512; ++t) {
      wait_ge(c_xp, 16ull * (u64)(t + 1), &sdead);
      const float* xrs = xring + (size_t)(t & 7) * 196608;
      float xp0[4], xp1[4], xpN[4];
      pref4t(xp0, xrs, colb0, mg, 3072);
      pref4t(xp1, xrs, colb1, mg, 3072);
      pref4t(xpN, xrs, 2048 + colbN, mg, 3072);
      // ---- P0: rz0(t), needs h0(t-1) ----
      if (t) wait_ge(c_n0, 16ull * (u64)t, &sdead);
      stage128(h0h + (size_t)((t + 3) & 3) * 65536, sA);
      float hp0[4], hp1[4];
      if (isR) { pref4t(hp0, h0f, colb0, mg, H); pref4t(hp1, h0f, colb1, mg, H); }
      __syncthreads();
      f4 acc[2] = { fz, fz };
      gemmNT<2>(sA, arow, wR, kg8, acc);
      apply_rz2(acc[0], colb0, mg, brz0, isR, hp0, xp0, rh0, z0f);
      apply_rz2(acc[1], colb1, mg, brz0, isR, hp1, xp1, rh0, z0f);
      signal_add(c_rz0);
      // ---- P1: n0(t), needs full rh0(t); ring-4 WAR vs L1 readers of slot t&3 ----
      wait_ge(c_rz0, 16ull * (u64)(t + 1), &sdead);
      if (t >= 4) {
        wait_ge(c_rz1, 16ull * (u64)(t - 3), &sdead);
        wait_ge(c_n1, 16ull * (u64)(t - 3), &sdead);
      }
      stage128(rh0, sA);
      float pz4[4], ph4[4];
      pref4t(pz4, z0f, colbN, mg, H);
      pref4t(ph4, h0f, colbN, mg, H);
      __syncthreads();
      f4 aN[1] = { fz };
      gemmNT<1>(sA, arow, wN, kg8, aN);
      apply_n2(aN[0], colbN, mg, bn0, pz4, ph4, xpN, h0f, h0h + (size_t)(t & 3) * 65536);
      signal_add(c_n0);
    }
  } else if (bid < 32) {
    // ---------- A: rz1(s) = sigmoid(Wrz1.[h0(s)|h1(s-1)]) ----------
    const int b2 = bid - 16;
    const bool isR = b2 < 8;
    const int colb0 = b2 * 128 + wsel * 32, colb1 = colb0 + 16;
    const _Float16* wH1[2] = { wrz1 + (size_t)(colb0 + rsub) * 2048 + 1024,
                               wrz1 + (size_t)(colb1 + rsub) * 2048 + 1024 };
    const _Float16* wH0[2] = { wrz1 + (size_t)(colb0 + rsub) * 2048,
                               wrz1 + (size_t)(colb1 + rsub) * 2048 };
    for (int s = 0; s < 512; ++s) {
      if (s) wait_ge(c_n1, 16ull * (u64)s, &sdead);
      stage128(h1h + (size_t)((s + 1) & 1) * 65536, sA);
      float hp0[4], hp1[4];
      if (isR) { pref4t(hp0, h1f, colb0, mg, H); pref4t(hp1, h1f, colb1, mg, H); }
      __syncthreads();
      f4 acc[2] = { fz, fz };
      gemmNT<2>(sA, arow, wH1, kg8, acc);       // h1-part while h0 pending
      wait_ge(c_n0, 16ull * (u64)(s + 1), &sdead);
      stage128(h0h + (size_t)(s & 3) * 65536, sA);
      __syncthreads();
      gemmNT<2>(sA, arow, wH0, kg8, acc);
      apply_rz2(acc[0], colb0, mg, brz1, isR, hp0, nullptr, rh1, z1f);
      apply_rz2(acc[1], colb1, mg, brz1, isR, hp1, nullptr, rh1, z1f);
      signal_add(c_rz1);
    }
  } else if (bid < 48) {
    // ---------- B: n1(s) = tanh(Wn1.[h0(s)|rh1(s)]); h1 update ----------
    const int b3 = bid - 32;
    const int colbN = b3 * 64 + wsel * 16;
    const _Float16* wNh0[1] = { wn1 + (size_t)(colbN + rsub) * 2048 };
    const _Float16* wNrh[1] = { wn1 + (size_t)(colbN + rsub) * 2048 + 1024 };
    for (int s = 0; s < 512; ++s) {
      wait_ge(c_n0, 16ull * (u64)(s + 1), &sdead);
      stage128(h0h + (size_t)(s & 3) * 65536, sA);
      __syncthreads();
      f4 aN[1] = { fz };
      gemmNT<1>(sA, arow, wNh0, kg8, aN);       // h0-part while rz1 pending
      wait_ge(c_rz1, 16ull * (u64)(s + 1), &sdead);
      stage128(rh1, sA);
      float pz4[4], ph4[4];
      pref4t(pz4, z1f, colbN, mg, H);
      pref4t(ph4, h1f, colbN, mg, H);
      __syncthreads();
      gemmNT<1>(sA, arow, wNrh, kg8, aN);
      apply_n2(aN[0], colbN, mg, bn1, pz4, ph4, nullptr, h1f, h1h + (size_t)(s & 1) * 65536);
      signal_add(c_n1);
    }
  } else {
    // ---------- xproj: block xb covers all 64 rows x cols [xb*192,+192), ring-8 ----------
    const int xb = bid - 48;
    const int rg = wsel, wq = mg;
    const float* xrow = x + (size_t)(rg * 16 + rsub) * 262144;
    const _Float16* wp[3];
    int colb[3];
#pragma unroll
    for (int c = 0; c < 3; ++c) {
      colb[c] = xb * 192 + (wq * 3 + c) * 16;
      wp[c] = (colb[c] < 2048) ? wrz0 + (size_t)(colb[c] + rsub) * 1536
                               : wn0 + (size_t)(colb[c] - 2048 + rsub) * 1536;
    }
    for (int t = 0; t < 512; ++t) {
      if (t >= 8) wait_ge(c_n0, 16ull * (u64)(t - 7), &sdead);   // ring WAR
      f4 acc[3] = { fz, fz, fz };
      const float* xt = xrow + (size_t)t * 512;
#pragma unroll
      for (int kw = 0; kw < 16; ++kw) {
        int k = kw * 32 + kg8;
        float4 f0 = *(const float4*)(xt + k);
        float4 f1 = *(const float4*)(xt + k + 4);
        h8 a;
        a[0] = (_Float16)f0.x; a[1] = (_Float16)f0.y; a[2] = (_Float16)f0.z; a[3] = (_Float16)f0.w;
        a[4] = (_Float16)f1.x; a[5] = (_Float16)f1.y; a[6] = (_Float16)f1.z; a[7] = (_Float16)f1.w;
#pragma unroll
        for (int c = 0; c < 3; ++c)
          acc[c] = MFMA16(a, *(const h8*)(wp[c] + k), acc[c]);
      }
      float* xrs = xring + (size_t)(t & 7) * 196608;
      const int r0 = rg * 16 + ((lane >> 4) << 2);
      const int csub = lane & 15;
#pragma unroll
      for (int c = 0; c < 3; ++c)
#pragma unroll
        for (int j = 0; j < 4; ++j)
          llc_st32(xrs + (size_t)(r0 + j) * 3072 + colb[c] + csub,
                   __float_as_uint(acc[c][j]));
      signal_add(c_xp);
    }
  }
}

// ---------------- final fc ----------------
__global__ __launch_bounds__(256) void fc_kernel(const float* __restrict__ h1f,
                                                 const float* __restrict__ wfc,
                                                 const float* __restrict__ bfc,
                                                 float* __restrict__ out) {
  const int bid = blockIdx.x;
#pragma unroll
  for (int rep = 0; rep < 2; ++rep) {
    int local = threadIdx.x + rep * 256;
    int b = local >> 3;
    int o = bid * 8 + (local & 7);
    const float4* hp = (const float4*)(h1f + (size_t)b * 1024);
    const float4* wp = (const float4*)(wfc + (size_t)o * 1024);
    float s = 0.f;
#pragma unroll 4
    for (int i2 = 0; i2 < 256; ++i2) {
      float4 hv = hp[i2], wv = wp[i2];
      s += hv.x * wv.x + hv.y * wv.y + hv.z * wv.z + hv.w * wv.w;
    }
    out[(size_t)b * 512 + o] = s + bfc[o];
  }
}

extern "C" void kernel_launch(void* const* d_in, const int* in_sizes, int n_in,
                              void* d_out, int out_size, void* d_ws, size_t ws_size,
                              hipStream_t stream) {
  const float* x    = (const float*)d_in[0];
  const float* Wrz0 = (const float*)d_in[1];
  const float* brz0 = (const float*)d_in[2];
  const float* Wn0  = (const float*)d_in[3];
  const float* bn0  = (const float*)d_in[4];
  const float* Wrz1 = (const float*)d_in[5];
  const float* brz1 = (const float*)d_in[6];
  const float* Wn1  = (const float*)d_in[7];
  const float* bn1  = (const float*)d_in[8];
  const float* Wfc  = (const float*)d_in[9];
  const float* bfc  = (const float*)d_in[10];
  float* out = (float*)d_out;
  char* ws = (char*)d_ws;

  _Float16* wrz0h = (_Float16*)(ws + OFF_WRZ0);
  _Float16* wn0h  = (_Float16*)(ws + OFF_WN0);
  _Float16* wrz1h = (_Float16*)(ws + OFF_WRZ1);
  _Float16* wn1h  = (_Float16*)(ws + OFF_WN1);
  _Float16* h0h   = (_Float16*)(ws + OFF_H0H);
  _Float16* h1h   = (_Float16*)(ws + OFF_H1H);
  _Float16* rh0   = (_Float16*)(ws + OFF_RH0);
  _Float16* rh1   = (_Float16*)(ws + OFF_RH1);
  float* h0f = (float*)(ws + OFF_H0F);
  float* h1f = (float*)(ws + OFF_H1F);
  float* z0f = (float*)(ws + OFF_Z0F);
  float* z1f = (float*)(ws + OFF_Z1F);
  float* xring = (float*)(ws + OFF_XR);
  u64* cnt = (u64*)(ws + OFF_CNT);

  prep_kernel<<<2048, 256, 0, stream>>>(Wrz0, Wn0, Wrz1, Wn1,
                                        wrz0h, wn0h, wrz1h, wn1h,
                                        (unsigned*)(ws + OFF_H0H));
  gru_main<<<64, 1024, 0, stream>>>(x, wrz0h, wn0h, wrz1h, wn1h,
                                    brz0, bn0, brz1, bn1,
                                    h0h, h1h, rh0, rh1,
                                    h0f, h1f, z0f, z1f, xring, cnt);
  fc_kernel<<<64, 256, 0, stream>>>(h1f, Wfc, bfc, out);
}

// Round 9
// 23027.168 us; speedup vs baseline: 1.9053x; 1.9053x over previous
//
#include <hip/hip_runtime.h>
#include <math.h>

typedef _Float16 h8 __attribute__((ext_vector_type(8)));
typedef float f4 __attribute__((ext_vector_type(4)));

#define H 1024

// ---- workspace layout (bytes) ----
#define OFF_WRZ0 0ull
#define OFF_WN0  6291456ull
#define OFF_WRZ1 9437184ull
#define OFF_WN1  17825792ull
#define OFF_H0BF 22020096ull   // fp16 [2][64][1024] master
#define OFF_H1BF 22282240ull   // fp16 [2][64][1024] master
#define OFF_RH0  22544384ull   // fp16 [64][1024] master
#define OFF_RH1  22675456ull   // fp16 [64][1024] master
#define OFF_H0F  22806528ull   // f32 [64][1024] master
#define OFF_H1F  23068672ull   // f32 [64][1024] master
#define OFF_Z0F  23330816ull   // f32 [64][1024] master
#define OFF_Z1F  23592960ull   // f32 [64][1024] master
#define OFF_CNT  23855104ull   // u64[5]: 0=c_rz0 1=c_n0 2=c_rz1 3=c_n1 4=init (stride 1)
#define OFF_INFO 23856128ull   // u32[128]
#define OFF_CCNT 23857152ull   // u64 [8 xcd][5 slot] stride 16 u64 (128B/slot)
#define OFF_CP   23863296ull   // copies [8 xcd][5 slot][131072 B]
#define CP_XCD_STRIDE 655360ull
#define ZERO_WORDS 460800      // (23863296 - 22020096)/4

// ---------------- LLC-bypass (agent-scope relaxed) helpers — r2/r3-proven ----------------
__device__ __forceinline__ unsigned long long llc_ld64(const void* p) {
  return __hip_atomic_load((const unsigned long long*)p, __ATOMIC_RELAXED, __HIP_MEMORY_SCOPE_AGENT);
}
__device__ __forceinline__ void llc_st64(void* p, unsigned long long v) {
  __hip_atomic_store((unsigned long long*)p, v, __ATOMIC_RELAXED, __HIP_MEMORY_SCOPE_AGENT);
}
__device__ __forceinline__ void llc_st32(void* p, unsigned v) {
  __hip_atomic_store((unsigned*)p, v, __ATOMIC_RELAXED, __HIP_MEMORY_SCOPE_AGENT);
}
__device__ __forceinline__ unsigned long long pack2f(float a, float b) {
  union { float f[2]; unsigned long long u; } x; x.f[0] = a; x.f[1] = b; return x.u;
}
__device__ __forceinline__ void unpack2f(unsigned long long v, float& a, float& b) {
  union { unsigned long long u; float f[2]; } x; x.u = v; a = x.f[0]; b = x.f[1];
}
__device__ __forceinline__ unsigned packh2(float a, float b) {
  union { _Float16 h[2]; unsigned u; } x; x.h[0] = (_Float16)a; x.h[1] = (_Float16)b; return x.u;
}

// ---------------- prep: weights fp32->fp16, zero comm region ----------------
__global__ __launch_bounds__(256) void prep_kernel(
    const float* __restrict__ wrz0f, const float* __restrict__ wn0f,
    const float* __restrict__ wrz1f, const float* __restrict__ wn1f,
    _Float16* __restrict__ wrz0, _Float16* __restrict__ wn0,
    _Float16* __restrict__ wrz1, _Float16* __restrict__ wn1,
    unsigned* __restrict__ zbase) {
  size_t i = (size_t)blockIdx.x * blockDim.x + threadIdx.x;
  size_t stride = (size_t)gridDim.x * blockDim.x;
  for (size_t k = i; k < 2048ull * 1536ull; k += stride) wrz0[k] = (_Float16)wrz0f[k];
  for (size_t k = i; k < 1024ull * 1536ull; k += stride) wn0[k]  = (_Float16)wn0f[k];
  for (size_t k = i; k < 2048ull * 2048ull; k += stride) wrz1[k] = (_Float16)wrz1f[k];
  for (size_t k = i; k < 1024ull * 2048ull; k += stride) wn1[k]  = (_Float16)wn1f[k];
  for (size_t k = i; k < (size_t)ZERO_WORDS; k += stride) zbase[k] = 0u;
}

// ---------------- flag wait/signal (r2/r3-proven) ----------------
__device__ __forceinline__ void wait_ge(unsigned long long* c, unsigned long long tgt) {
  if (threadIdx.x == 0) {
    int g = 0;
    while (__hip_atomic_load(c, __ATOMIC_RELAXED, __HIP_MEMORY_SCOPE_AGENT) < tgt) {
      if (++g > (1 << 21)) break;      // fail loud (absmax), never hang
      __builtin_amdgcn_s_sleep(2);
    }
  }
  __syncthreads();
}
// __syncthreads drains vmcnt(0) -> all LLC stores visible before thread 0 bumps.
__device__ __forceinline__ void signal(unsigned long long* c) {
  __syncthreads();
  if (threadIdx.x == 0)
    __hip_atomic_fetch_add(c, 1ull, __ATOMIC_RELAXED, __HIP_MEMORY_SCOPE_AGENT);
}

// ---------------- cooperative role-private per-XCD copy: master(LLC) -> L2 copy ----------------
// m same-XCD SAME-ROLE blocks each copy a strided slice, arrive on a role-private
// counter, wait target, then buffer_inv sc0 so normal loads see the fresh L2 copy.
// (chain proven in r3; role-privacy is the r9 change)
__device__ __forceinline__ void copy_tensor(const void* __restrict__ master,
                                            void* __restrict__ cp,
                                            int rank, int m,
                                            unsigned long long* ccnt,
                                            unsigned long long target) {
  const unsigned long long* src = (const unsigned long long*)master;
  unsigned long long* dst = (unsigned long long*)cp;
  for (int u = rank * 1024 + (int)threadIdx.x; u < 16384; u += m * 1024)
    dst[u] = llc_ld64(src + u);
  __syncthreads();   // drain vmcnt for all waves (stores at L2)
  if (threadIdx.x == 0) {
    __hip_atomic_fetch_add(ccnt, 1ull, __ATOMIC_RELAXED, __HIP_MEMORY_SCOPE_AGENT);
    int g = 0;
    while (__hip_atomic_load(ccnt, __ATOMIC_RELAXED, __HIP_MEMORY_SCOPE_AGENT) < target) {
      if (++g > (1 << 21)) break;
      __builtin_amdgcn_s_sleep(2);
    }
  }
  __syncthreads();
  asm volatile("buffer_inv sc0" ::: "memory");  // invalidate this CU's L1 only
}

// ---------------- GEMM over an L2-resident copy [64][1024] fp16 (r3-proven) ----------------
template<int NT>
__device__ __forceinline__ void gemm_cp(const _Float16* __restrict__ A,
                                        const _Float16* const* wps, int coff, f4* acc) {
  const int lane = threadIdx.x & 63, wv = threadIdx.x >> 6;
  const int kwq = wv & 3, mw = wv >> 2;
  const int rsub = lane & 15, kg = (lane >> 4) << 3;
  const _Float16* ap = A + (size_t)(mw * 16 + rsub) * 1024 + kwq * 256 + kg;
#pragma unroll
  for (int k0 = 0; k0 < 256; k0 += 32) {
    h8 a = *(const h8*)(ap + k0);
    int kc = coff + kwq * 256 + k0 + kg;
#pragma unroll
    for (int c = 0; c < NT; ++c) {
      h8 wf = *(const h8*)(wps[c] + kc);
      acc[c] = __builtin_amdgcn_mfma_f32_16x16x32_f16(a, wf, acc[c], 0, 0, 0);
    }
  }
}

// x-part GEMM (layer0, K=512, fp32 x converted in-register); rz(2) + n(1)
__device__ __forceinline__ void gemm_x(const float* __restrict__ x, int t,
                                       const _Float16* __restrict__ wr0,
                                       const _Float16* __restrict__ wr1,
                                       const _Float16* __restrict__ wn,
                                       f4* aRZ, f4* aN) {
  const int lane = threadIdx.x & 63, wv = threadIdx.x >> 6;
  const int kwq = wv & 3, mw = wv >> 2;
  const int rsub = lane & 15, kg = (lane >> 4) << 3;
  const float* xb = x + (size_t)(mw * 16 + rsub) * 262144 + (size_t)t * 512;
#pragma unroll
  for (int k0 = 0; k0 < 128; k0 += 32) {
    int k = kwq * 128 + k0 + kg;
    float4 f0 = *(const float4*)(xb + k);
    float4 f1 = *(const float4*)(xb + k + 4);
    h8 a;
    a[0] = (_Float16)f0.x; a[1] = (_Float16)f0.y; a[2] = (_Float16)f0.z; a[3] = (_Float16)f0.w;
    a[4] = (_Float16)f1.x; a[5] = (_Float16)f1.y; a[6] = (_Float16)f1.z; a[7] = (_Float16)f1.w;
    aRZ[0] = __builtin_amdgcn_mfma_f32_16x16x32_f16(a, *(const h8*)(wr0 + k), aRZ[0], 0, 0, 0);
    aRZ[1] = __builtin_amdgcn_mfma_f32_16x16x32_f16(a, *(const h8*)(wr1 + k), aRZ[1], 0, 0, 0);
    aN[0]  = __builtin_amdgcn_mfma_f32_16x16x32_f16(a, *(const h8*)(wn + k),  aN[0], 0, 0, 0);
  }
}

// per-wave partials -> LDS red[kwq][64 rows][<=32 cols], stride 33 (r3-proven)
template<int NT>
__device__ __forceinline__ void red_write(float* __restrict__ red, const f4* acc) {
  const int lane = threadIdx.x & 63, wv = threadIdx.x >> 6;
  const int kwq = wv & 3, mw = wv >> 2;
  const int rsub = lane & 15, rg = lane >> 4;
#pragma unroll
  for (int c = 0; c < NT; ++c)
#pragma unroll
    for (int j = 0; j < 4; ++j)
      red[(size_t)(kwq * 64 + mw * 16 + rg * 4 + j) * 33 + c * 16 + rsub] = acc[c][j];
}

// rz reduce+apply (r3-proven)
__device__ __forceinline__ void reduce_rz(const float* __restrict__ red, int cb,
    const float* __restrict__ bias, const float* __restrict__ hf,
    _Float16* __restrict__ rh, float* __restrict__ zf) {
  const int tid = threadIdx.x;
  const int row = tid >> 4, cp = (tid & 15) << 1;
  float v0 = 0.f, v1 = 0.f;
#pragma unroll
  for (int q = 0; q < 4; ++q) {
    const float* rr = red + (size_t)(q * 64 + row) * 33 + cp;
    v0 += rr[0]; v1 += rr[1];
  }
  v0 += bias[cb + cp]; v1 += bias[cb + cp + 1];
  float s0 = 1.f / (1.f + expf(-v0));
  float s1 = 1.f / (1.f + expf(-v1));
  if (cb < 1024) {
    float h0v, h1v;
    unpack2f(llc_ld64(hf + (size_t)row * H + cb + cp), h0v, h1v);
    llc_st32(rh + (size_t)row * H + cb + cp, packh2(s0 * h0v, s1 * h1v));
  } else {
    llc_st64(zf + (size_t)row * H + (cb - 1024) + cp, pack2f(s0, s1));
  }
}

// n reduce+apply + h update (r3-proven)
__device__ __forceinline__ void reduce_n(const float* __restrict__ red, int nb,
    const float* __restrict__ bias, const float* __restrict__ zf,
    float* __restrict__ hf, _Float16* __restrict__ hb) {
  const int tid = threadIdx.x;
  if (tid < 512) {
    const int row = tid >> 3, cp = (tid & 7) << 1;
    float v0 = 0.f, v1 = 0.f;
#pragma unroll
    for (int q = 0; q < 4; ++q) {
      const float* rr = red + (size_t)(q * 64 + row) * 33 + cp;
      v0 += rr[0]; v1 += rr[1];
    }
    v0 += bias[nb + cp]; v1 += bias[nb + cp + 1];
    float n0 = tanhf(v0), n1 = tanhf(v1);
    float z0, z1, h0v, h1v;
    unpack2f(llc_ld64(zf + (size_t)row * H + nb + cp), z0, z1);
    unpack2f(llc_ld64(hf + (size_t)row * H + nb + cp), h0v, h1v);
    float o0 = (1.f - z0) * n0 + z0 * h0v;
    float o1 = (1.f - z1) * n1 + z1 * h1v;
    llc_st64(hf + (size_t)row * H + nb + cp, pack2f(o0, o1));
    llc_st32(hb + (size_t)row * H + nb + cp, packh2(o0, o1));
  }
}

// ---------------- persistent GRU kernel ----------------
// cnt[0]=c_rz0 cnt[1]=c_n0 cnt[2]=c_rz1 cnt[3]=c_n1 cnt[4]=init
// ccnt[xcd][slot]: 0=L0:h0, 1=L0:rh0, 2=L1:h1, 3=L1:h0, 4=L1:rh1 (role-private!)
__global__ __launch_bounds__(1024) void gru_main(const float* __restrict__ x,
    const _Float16* __restrict__ wrz0, const _Float16* __restrict__ wn0,
    const _Float16* __restrict__ wrz1, const _Float16* __restrict__ wn1,
    const float* __restrict__ brz0, const float* __restrict__ bn0,
    const float* __restrict__ brz1, const float* __restrict__ bn1,
    _Float16* __restrict__ h0bf, _Float16* __restrict__ h1bf,
    _Float16* __restrict__ rh0, _Float16* __restrict__ rh1,
    float* __restrict__ h0f, float* __restrict__ h1f,
    float* __restrict__ z0f, float* __restrict__ z1f,
    unsigned long long* __restrict__ cnt, unsigned* __restrict__ info,
    unsigned long long* __restrict__ ccnt_all, char* __restrict__ cpbase) {
  __shared__ float red[256 * 33];
  __shared__ int sh_meta[3];
  const int bid = blockIdx.x;
  const int tid = threadIdx.x;
  const int myrole = (bid < 64) ? 0 : 1;

  // ---- discovery: physical XCD + rank/count within (XCD, role) — r3-proven ----
  if (tid == 0) {
    unsigned xcc;
    asm volatile("s_getreg_b32 %0, hwreg(HW_REG_XCC_ID)" : "=s"(xcc));
    xcc &= 7u;
    llc_st32(&info[bid], 0x100u | xcc);
    asm volatile("s_waitcnt vmcnt(0)" ::: "memory");
    __hip_atomic_fetch_add(&cnt[4], 1ull, __ATOMIC_RELAXED, __HIP_MEMORY_SCOPE_AGENT);
    int g = 0;
    while (__hip_atomic_load(&cnt[4], __ATOMIC_RELAXED, __HIP_MEMORY_SCOPE_AGENT) < 128ull) {
      if (++g > (1 << 22)) break;
      __builtin_amdgcn_s_sleep(2);
    }
    int rankR = 0, mR = 0;
    for (int b = 0; b < 128; ++b) {
      unsigned v = (unsigned)__hip_atomic_load(&info[b], __ATOMIC_RELAXED, __HIP_MEMORY_SCOPE_AGENT);
      if ((v & 7u) == xcc && ((b < 64) ? 0 : 1) == myrole) {
        if (b < bid) rankR++;
        mR++;
      }
    }
    sh_meta[0] = (int)xcc; sh_meta[1] = rankR; sh_meta[2] = mR;
  }
  __syncthreads();
  const int xcd = sh_meta[0], rankR = sh_meta[1], mR = sh_meta[2];
  unsigned long long* cc = ccnt_all + (size_t)xcd * 5 * 16;
  char* cpx = cpbase + (size_t)xcd * CP_XCD_STRIDE;
  _Float16* cpS[5];
#pragma unroll
  for (int i = 0; i < 5; ++i) cpS[i] = (_Float16*)(cpx + (size_t)i * 131072);
  const int rsub = tid & 15;

  if (myrole == 0) {
    // ---------- layer 0, step t ----------
    const int cb = bid * 32, nb = bid * 16;
    const _Float16* wpsRZ[2] = { wrz0 + (size_t)(cb + rsub) * 1536,
                                 wrz0 + (size_t)(cb + 16 + rsub) * 1536 };
    const _Float16* wpsN[1] = { wn0 + (size_t)(nb + rsub) * 1536 };
    for (int t = 0; t < 512; ++t) {
      f4 aRZ[2] = { f4{0.f,0.f,0.f,0.f}, f4{0.f,0.f,0.f,0.f} };
      f4 aN[1] = { f4{0.f,0.f,0.f,0.f} };
      gemm_x(x, t, wpsRZ[0], wpsRZ[1], wpsN[0], aRZ, aN);   // no dependency
      // phase A: rz0(t)  (needs h0(t-1); t=0 -> zeros, skip)
      wait_ge(&cnt[1], 64ull * (unsigned long long)t);
      if (t >= 1) {
        copy_tensor(h0bf + (size_t)((t - 1) & 1) * 65536, cpS[0],
                    rankR, mR, &cc[0 * 16], (unsigned long long)mR * t);
        gemm_cp<2>(cpS[0], wpsRZ, 512, aRZ);
      }
      red_write<2>(red, aRZ);
      __syncthreads();
      reduce_rz(red, cb, brz0, h0f, rh0, z0f);
      signal(&cnt[0]);
      // phase B: n0(t)  (needs rh0(t); t=0 -> rh0==0, skip gemm)
      wait_ge(&cnt[0], 64ull * (unsigned long long)(t + 1));
      if (t >= 1) wait_ge(&cnt[3], 64ull * (unsigned long long)(t - 1));  // h0bf WAR
      if (t >= 1) {
        copy_tensor(rh0, cpS[1], rankR, mR, &cc[1 * 16], (unsigned long long)mR * t);
        gemm_cp<1>(cpS[1], wpsN, 512, aN);
      }
      red_write<1>(red, aN);
      __syncthreads();
      reduce_n(red, nb, bn0, z0f, h0f, h0bf + (size_t)(t & 1) * 65536);
      signal(&cnt[1]);
    }
  } else {
    // ---------- layer 1, step s = t-1 ----------
    const int b = bid - 64, cb = b * 32, nb = b * 16;
    const _Float16* wps3[3] = { wrz1 + (size_t)(cb + rsub) * 2048,
                                wrz1 + (size_t)(cb + 16 + rsub) * 2048,
                                wn1  + (size_t)(nb + rsub) * 2048 };
    for (int t = 1; t <= 512; ++t) {
      const int s = t - 1;
      f4 acc3[3] = { f4{0.f,0.f,0.f,0.f}, f4{0.f,0.f,0.f,0.f}, f4{0.f,0.f,0.f,0.f} };
      // phase A: rz1(s): h1(s-1)-part (s=0 -> zeros, skip)
      wait_ge(&cnt[3], 64ull * (unsigned long long)s);
      if (s >= 1) {
        copy_tensor(h1bf + (size_t)((s - 1) & 1) * 65536, cpS[2],
                    rankR, mR, &cc[2 * 16], (unsigned long long)mR * s);
        gemm_cp<2>(cpS[2], wps3, 1024, acc3);
      }
      // h0(s)-part for rz1 AND n1 (fused NT=3, role-private copy slot 3)
      wait_ge(&cnt[1], 64ull * (unsigned long long)t);
      copy_tensor(h0bf + (size_t)((t - 1) & 1) * 65536, cpS[3],
                  rankR, mR, &cc[3 * 16], (unsigned long long)mR * t);
      gemm_cp<3>(cpS[3], wps3, 0, acc3);
      red_write<2>(red, acc3);
      __syncthreads();
      reduce_rz(red, cb, brz1, h1f, rh1, z1f);
      signal(&cnt[2]);
      // phase B: n1(s) rh-part (s=0 -> rh1==0, skip gemm)
      wait_ge(&cnt[2], 64ull * (unsigned long long)t);
      if (s >= 1) {
        copy_tensor(rh1, cpS[4], rankR, mR, &cc[4 * 16], (unsigned long long)mR * s);
        gemm_cp<1>(cpS[4], wps3 + 2, 1024, acc3 + 2);
      }
      red_write<1>(red, acc3 + 2);
      __syncthreads();
      reduce_n(red, nb, bn1, z1f, h1f, h1bf + (size_t)(s & 1) * 65536);
      signal(&cnt[3]);
    }
  }
}

// ---------------- final fc: out[64,512] = h1 @ Wfc^T + bfc ----------------
__global__ __launch_bounds__(256) void fc_kernel(const float* __restrict__ h1f,
                                                 const float* __restrict__ wfc,
                                                 const float* __restrict__ bfc,
                                                 float* __restrict__ out) {
  const int bid = blockIdx.x;  // 64 blocks x 8 cols
#pragma unroll
  for (int rep = 0; rep < 2; ++rep) {
    int local = threadIdx.x + rep * 256;
    int b = local >> 3;
    int o = bid * 8 + (local & 7);
    const float4* hp = (const float4*)(h1f + (size_t)b * 1024);
    const float4* wp = (const float4*)(wfc + (size_t)o * 1024);
    float s = 0.f;
#pragma unroll 4
    for (int i2 = 0; i2 < 256; ++i2) {
      float4 hv = hp[i2], wv = wp[i2];
      s += hv.x * wv.x + hv.y * wv.y + hv.z * wv.z + hv.w * wv.w;
    }
    out[(size_t)b * 512 + o] = s + bfc[o];
  }
}

extern "C" void kernel_launch(void* const* d_in, const int* in_sizes, int n_in,
                              void* d_out, int out_size, void* d_ws, size_t ws_size,
                              hipStream_t stream) {
  const float* x    = (const float*)d_in[0];
  const float* Wrz0 = (const float*)d_in[1];
  const float* brz0 = (const float*)d_in[2];
  const float* Wn0  = (const float*)d_in[3];
  const float* bn0  = (const float*)d_in[4];
  const float* Wrz1 = (const float*)d_in[5];
  const float* brz1 = (const float*)d_in[6];
  const float* Wn1  = (const float*)d_in[7];
  const float* bn1  = (const float*)d_in[8];
  const float* Wfc  = (const float*)d_in[9];
  const float* bfc  = (const float*)d_in[10];
  float* out = (float*)d_out;
  char* ws = (char*)d_ws;

  _Float16* wrz0h = (_Float16*)(ws + OFF_WRZ0);
  _Float16* wn0h  = (_Float16*)(ws + OFF_WN0);
  _Float16* wrz1h = (_Float16*)(ws + OFF_WRZ1);
  _Float16* wn1h  = (_Float16*)(ws + OFF_WN1);
  _Float16* h0bf  = (_Float16*)(ws + OFF_H0BF);
  _Float16* h1bf  = (_Float16*)(ws + OFF_H1BF);
  _Float16* rh0   = (_Float16*)(ws + OFF_RH0);
  _Float16* rh1   = (_Float16*)(ws + OFF_RH1);
  float* h0f = (float*)(ws + OFF_H0F);
  float* h1f = (float*)(ws + OFF_H1F);
  float* z0f = (float*)(ws + OFF_Z0F);
  float* z1f = (float*)(ws + OFF_Z1F);
  unsigned long long* cnt = (unsigned long long*)(ws + OFF_CNT);
  unsigned* info = (unsigned*)(ws + OFF_INFO);
  unsigned long long* ccnt = (unsigned long long*)(ws + OFF_CCNT);
  char* cpbase = ws + OFF_CP;

  prep_kernel<<<2048, 256, 0, stream>>>(Wrz0, Wn0, Wrz1, Wn1,
                                        wrz0h, wn0h, wrz1h, wn1h,
                                        (unsigned*)(ws + OFF_H0BF));
  gru_main<<<128, 1024, 0, stream>>>(x, wrz0h, wn0h, wrz1h, wn1h,
                                     brz0, bn0, brz1, bn1,
                                     h0bf, h1bf, rh0, rh1,
                                     h0f, h1f, z0f, z1f,
                                     cnt, info, ccnt, cpbase);
  fc_kernel<<<64, 256, 0, stream>>>(h1f, Wfc, bfc, out);
}

// Round 10
// 22249.495 us; speedup vs baseline: 1.9718x; 1.0350x over previous
//
#include <hip/hip_runtime.h>
#include <math.h>

typedef _Float16 h8 __attribute__((ext_vector_type(8)));
typedef float f4 __attribute__((ext_vector_type(4)));
typedef unsigned long long u64;

#define H 1024

// ---- workspace layout (bytes) ----
#define OFF_WRZ0 0ull
#define OFF_WN0  6291456ull
#define OFF_WRZ1 9437184ull
#define OFF_WN1  17825792ull
#define OFF_H0BF 22020096ull   // fp16 [2][64][1024] master
#define OFF_H1BF 22282240ull   // fp16 [2][64][1024] master
#define OFF_RH0  22544384ull   // fp16 [64][1024] master
#define OFF_RH1  22675456ull   // fp16 [64][1024] master
#define OFF_H0F  22806528ull   // f32 [64][1024] master
#define OFF_H1F  23068672ull   // f32 [64][1024] master
#define OFF_Z0F  23330816ull   // f32 [64][1024] master
#define OFF_Z1F  23592960ull   // f32 [64][1024] master
#define OFF_CNT  23855104ull   // u64[5]: 0=c_rz0 1=c_n0 2=c_rz1 3=c_n1 4=init
#define OFF_INFO 23856128ull   // u32[128]
#define OFF_CCNT 23857152ull   // u64 [8 xcd][5 slot] stride 16 u64 (128B/slot)
#define OFF_CP   23863296ull   // copies [8 xcd][5 slot][131072 B]
#define CP_XCD_STRIDE 655360ull
#define ZERO_WORDS 460800      // (23863296 - 22020096)/4

// ---------------- LLC-bypass (agent-scope relaxed) helpers — r2/r3/r9-proven ----------------
__device__ __forceinline__ u64 llc_ld64(const void* p) {
  return __hip_atomic_load((const u64*)p, __ATOMIC_RELAXED, __HIP_MEMORY_SCOPE_AGENT);
}
__device__ __forceinline__ void llc_st64(void* p, u64 v) {
  __hip_atomic_store((u64*)p, v, __ATOMIC_RELAXED, __HIP_MEMORY_SCOPE_AGENT);
}
__device__ __forceinline__ void llc_st32(void* p, unsigned v) {
  __hip_atomic_store((unsigned*)p, v, __ATOMIC_RELAXED, __HIP_MEMORY_SCOPE_AGENT);
}
__device__ __forceinline__ u64 pack2f(float a, float b) {
  union { float f[2]; u64 u; } x; x.f[0] = a; x.f[1] = b; return x.u;
}
__device__ __forceinline__ void unpack2f(u64 v, float& a, float& b) {
  union { u64 u; float f[2]; } x; x.u = v; a = x.f[0]; b = x.f[1];
}
__device__ __forceinline__ unsigned packh2(float a, float b) {
  union { _Float16 h[2]; unsigned u; } x; x.h[0] = (_Float16)a; x.h[1] = (_Float16)b; return x.u;
}

// ---------------- prep: weights fp32->fp16, zero comm region ----------------
__global__ __launch_bounds__(256) void prep_kernel(
    const float* __restrict__ wrz0f, const float* __restrict__ wn0f,
    const float* __restrict__ wrz1f, const float* __restrict__ wn1f,
    _Float16* __restrict__ wrz0, _Float16* __restrict__ wn0,
    _Float16* __restrict__ wrz1, _Float16* __restrict__ wn1,
    unsigned* __restrict__ zbase) {
  size_t i = (size_t)blockIdx.x * blockDim.x + threadIdx.x;
  size_t stride = (size_t)gridDim.x * blockDim.x;
  for (size_t k = i; k < 2048ull * 1536ull; k += stride) wrz0[k] = (_Float16)wrz0f[k];
  for (size_t k = i; k < 1024ull * 1536ull; k += stride) wn0[k]  = (_Float16)wn0f[k];
  for (size_t k = i; k < 2048ull * 2048ull; k += stride) wrz1[k] = (_Float16)wrz1f[k];
  for (size_t k = i; k < 1024ull * 2048ull; k += stride) wn1[k]  = (_Float16)wn1f[k];
  for (size_t k = i; k < (size_t)ZERO_WORDS; k += stride) zbase[k] = 0u;
}

// ---------------- flag wait/signal (r2/r3-proven) ----------------
__device__ __forceinline__ void wait_ge(u64* c, u64 tgt) {
  if (threadIdx.x == 0) {
    int g = 0;
    while (__hip_atomic_load(c, __ATOMIC_RELAXED, __HIP_MEMORY_SCOPE_AGENT) < tgt) {
      if (++g > (1 << 21)) break;      // fail loud (absmax), never hang
      __builtin_amdgcn_s_sleep(2);
    }
  }
  __syncthreads();
}
// __syncthreads drains vmcnt(0) -> all LLC stores visible before thread 0 bumps.
__device__ __forceinline__ void signal(u64* c) {
  __syncthreads();
  if (threadIdx.x == 0)
    __hip_atomic_fetch_add(c, 1ull, __ATOMIC_RELAXED, __HIP_MEMORY_SCOPE_AGENT);
}

// ---------------- split copy: issue (loads+stores) / crew_sync (drain+arrive+poll+inv) ----------------
__device__ __forceinline__ void copy_issue(const void* __restrict__ master,
                                           void* __restrict__ cp, int rank, int m) {
  const u64* src = (const u64*)master;
  u64* dst = (u64*)cp;
  for (int u = rank * 1024 + (int)threadIdx.x; u < 16384; u += m * 1024)
    dst[u] = llc_ld64(src + u);
}
__device__ __forceinline__ void crew_sync(u64* ccnt, u64 target) {
  __syncthreads();   // drain vmcnt: copy stores at L2
  if (threadIdx.x == 0) {
    __hip_atomic_fetch_add(ccnt, 1ull, __ATOMIC_RELAXED, __HIP_MEMORY_SCOPE_AGENT);
    int g = 0;
    while (__hip_atomic_load(ccnt, __ATOMIC_RELAXED, __HIP_MEMORY_SCOPE_AGENT) < target) {
      if (++g > (1 << 21)) break;
      __builtin_amdgcn_s_sleep(2);
    }
  }
  __syncthreads();
  asm volatile("buffer_inv sc0" ::: "memory");  // L1-only invalidate
}

// ---------------- GEMM over an L2-resident copy [64][1024] fp16 (r3/r9-proven) ----------------
template<int NT>
__device__ __forceinline__ void gemm_cp(const _Float16* __restrict__ A,
                                        const _Float16* const* wps, int coff, f4* acc) {
  const int lane = threadIdx.x & 63, wv = threadIdx.x >> 6;
  const int kwq = wv & 3, mw = wv >> 2;
  const int rsub = lane & 15, kg = (lane >> 4) << 3;
  const _Float16* ap = A + (size_t)(mw * 16 + rsub) * 1024 + kwq * 256 + kg;
#pragma unroll
  for (int k0 = 0; k0 < 256; k0 += 32) {
    h8 a = *(const h8*)(ap + k0);
    int kc = coff + kwq * 256 + k0 + kg;
#pragma unroll
    for (int c = 0; c < NT; ++c) {
      h8 wf = *(const h8*)(wps[c] + kc);
      acc[c] = __builtin_amdgcn_mfma_f32_16x16x32_f16(a, wf, acc[c], 0, 0, 0);
    }
  }
}

// x-part GEMM (layer0, K=512, fp32 x converted in-register); rz(2) + n(1)
__device__ __forceinline__ void gemm_x(const float* __restrict__ x, int t,
                                       const _Float16* __restrict__ wr0,
                                       const _Float16* __restrict__ wr1,
                                       const _Float16* __restrict__ wn,
                                       f4* aRZ, f4* aN) {
  const int lane = threadIdx.x & 63, wv = threadIdx.x >> 6;
  const int kwq = wv & 3, mw = wv >> 2;
  const int rsub = lane & 15, kg = (lane >> 4) << 3;
  const float* xb = x + (size_t)(mw * 16 + rsub) * 262144 + (size_t)t * 512;
#pragma unroll
  for (int k0 = 0; k0 < 128; k0 += 32) {
    int k = kwq * 128 + k0 + kg;
    float4 f0 = *(const float4*)(xb + k);
    float4 f1 = *(const float4*)(xb + k + 4);
    h8 a;
    a[0] = (_Float16)f0.x; a[1] = (_Float16)f0.y; a[2] = (_Float16)f0.z; a[3] = (_Float16)f0.w;
    a[4] = (_Float16)f1.x; a[5] = (_Float16)f1.y; a[6] = (_Float16)f1.z; a[7] = (_Float16)f1.w;
    aRZ[0] = __builtin_amdgcn_mfma_f32_16x16x32_f16(a, *(const h8*)(wr0 + k), aRZ[0], 0, 0, 0);
    aRZ[1] = __builtin_amdgcn_mfma_f32_16x16x32_f16(a, *(const h8*)(wr1 + k), aRZ[1], 0, 0, 0);
    aN[0]  = __builtin_amdgcn_mfma_f32_16x16x32_f16(a, *(const h8*)(wn + k),  aN[0], 0, 0, 0);
  }
}

// per-wave partials -> LDS red[kwq][64 rows][<=32 cols], stride 33 (proven)
template<int NT>
__device__ __forceinline__ void red_write(float* __restrict__ red, const f4* acc) {
  const int lane = threadIdx.x & 63, wv = threadIdx.x >> 6;
  const int kwq = wv & 3, mw = wv >> 2;
  const int rsub = lane & 15, rg = lane >> 4;
#pragma unroll
  for (int c = 0; c < NT; ++c)
#pragma unroll
    for (int j = 0; j < 4; ++j)
      red[(size_t)(kwq * 64 + mw * 16 + rg * 4 + j) * 33 + c * 16 + rsub] = acc[c][j];
}

// ---------------- gate prefetch (issued right after phase-entry wait) ----------------
__device__ __forceinline__ u64 pre_rz(const float* __restrict__ hf, int cb) {
  if (cb >= 1024) return 0ull;
  int row = threadIdx.x >> 4, cp = (threadIdx.x & 15) << 1;
  return llc_ld64(hf + (size_t)row * H + cb + cp);
}
__device__ __forceinline__ void pre_n(const float* __restrict__ zf,
                                      const float* __restrict__ hf, int nb,
                                      u64& zv, u64& hv) {
  if (threadIdx.x < 512) {
    int row = threadIdx.x >> 3, cp = (threadIdx.x & 7) << 1;
    zv = llc_ld64(zf + (size_t)row * H + nb + cp);
    hv = llc_ld64(hf + (size_t)row * H + nb + cp);
  }
}

// rz reduce+apply (r9 math; h gate value pre-fetched)
__device__ __forceinline__ void reduce_rz(const float* __restrict__ red, int cb,
    const float* __restrict__ bias, u64 hpre,
    _Float16* __restrict__ rh, float* __restrict__ zf) {
  const int tid = threadIdx.x;
  const int row = tid >> 4, cp = (tid & 15) << 1;
  float v0 = 0.f, v1 = 0.f;
#pragma unroll
  for (int q = 0; q < 4; ++q) {
    const float* rr = red + (size_t)(q * 64 + row) * 33 + cp;
    v0 += rr[0]; v1 += rr[1];
  }
  v0 += bias[cb + cp]; v1 += bias[cb + cp + 1];
  float s0 = 1.f / (1.f + expf(-v0));
  float s1 = 1.f / (1.f + expf(-v1));
  if (cb < 1024) {
    float h0v, h1v;
    unpack2f(hpre, h0v, h1v);
    llc_st32(rh + (size_t)row * H + cb + cp, packh2(s0 * h0v, s1 * h1v));
  } else {
    llc_st64(zf + (size_t)row * H + (cb - 1024) + cp, pack2f(s0, s1));
  }
}

// n reduce+apply + h update (r9 math; z/h gate values pre-fetched)
__device__ __forceinline__ void reduce_n(const float* __restrict__ red, int nb,
    const float* __restrict__ bias, u64 zpre, u64 hpre,
    float* __restrict__ hf, _Float16* __restrict__ hb) {
  const int tid = threadIdx.x;
  if (tid < 512) {
    const int row = tid >> 3, cp = (tid & 7) << 1;
    float v0 = 0.f, v1 = 0.f;
#pragma unroll
    for (int q = 0; q < 4; ++q) {
      const float* rr = red + (size_t)(q * 64 + row) * 33 + cp;
      v0 += rr[0]; v1 += rr[1];
    }
    v0 += bias[nb + cp]; v1 += bias[nb + cp + 1];
    float n0 = tanhf(v0), n1 = tanhf(v1);
    float z0, z1, h0v, h1v;
    unpack2f(zpre, z0, z1);
    unpack2f(hpre, h0v, h1v);
    float o0 = (1.f - z0) * n0 + z0 * h0v;
    float o1 = (1.f - z1) * n1 + z1 * h1v;
    llc_st64(hf + (size_t)row * H + nb + cp, pack2f(o0, o1));
    llc_st32(hb + (size_t)row * H + nb + cp, packh2(o0, o1));
  }
}

// ---------------- persistent GRU kernel ----------------
// cnt[0]=c_rz0 cnt[1]=c_n0 cnt[2]=c_rz1 cnt[3]=c_n1 cnt[4]=init
// ccnt[xcd][slot]: 0=L0:h0, 1=L0:rh0, 3=L1:{h1+h0 combined}, 4=L1:rh1 (role-private)
__global__ __launch_bounds__(1024) void gru_main(const float* __restrict__ x,
    const _Float16* __restrict__ wrz0, const _Float16* __restrict__ wn0,
    const _Float16* __restrict__ wrz1, const _Float16* __restrict__ wn1,
    const float* __restrict__ brz0, const float* __restrict__ bn0,
    const float* __restrict__ brz1, const float* __restrict__ bn1,
    _Float16* __restrict__ h0bf, _Float16* __restrict__ h1bf,
    _Float16* __restrict__ rh0, _Float16* __restrict__ rh1,
    float* __restrict__ h0f, float* __restrict__ h1f,
    float* __restrict__ z0f, float* __restrict__ z1f,
    u64* __restrict__ cnt, unsigned* __restrict__ info,
    u64* __restrict__ ccnt_all, char* __restrict__ cpbase) {
  __shared__ float red[256 * 33];
  __shared__ int sh_meta[3];
  const int bid = blockIdx.x;
  const int tid = threadIdx.x;
  const int myrole = (bid < 64) ? 0 : 1;

  // ---- discovery: physical XCD + rank/count within (XCD, role) — r3/r9-proven ----
  if (tid == 0) {
    unsigned xcc;
    asm volatile("s_getreg_b32 %0, hwreg(HW_REG_XCC_ID)" : "=s"(xcc));
    xcc &= 7u;
    llc_st32(&info[bid], 0x100u | xcc);
    asm volatile("s_waitcnt vmcnt(0)" ::: "memory");
    __hip_atomic_fetch_add(&cnt[4], 1ull, __ATOMIC_RELAXED, __HIP_MEMORY_SCOPE_AGENT);
    int g = 0;
    while (__hip_atomic_load(&cnt[4], __ATOMIC_RELAXED, __HIP_MEMORY_SCOPE_AGENT) < 128ull) {
      if (++g > (1 << 22)) break;
      __builtin_amdgcn_s_sleep(2);
    }
    int rankR = 0, mR = 0;
    for (int b = 0; b < 128; ++b) {
      unsigned v = (unsigned)__hip_atomic_load(&info[b], __ATOMIC_RELAXED, __HIP_MEMORY_SCOPE_AGENT);
      if ((v & 7u) == xcc && ((b < 64) ? 0 : 1) == myrole) {
        if (b < bid) rankR++;
        mR++;
      }
    }
    sh_meta[0] = (int)xcc; sh_meta[1] = rankR; sh_meta[2] = mR;
  }
  __syncthreads();
  const int xcd = sh_meta[0], rankR = sh_meta[1], mR = sh_meta[2];
  u64* cc = ccnt_all + (size_t)xcd * 5 * 16;
  char* cpx = cpbase + (size_t)xcd * CP_XCD_STRIDE;
  _Float16* cpS[5];
#pragma unroll
  for (int i = 0; i < 5; ++i) cpS[i] = (_Float16*)(cpx + (size_t)i * 131072);
  const int rsub = tid & 15;

  if (myrole == 0) {
    // ---------- layer 0, step t ----------
    const int cb = bid * 32, nb = bid * 16;
    const _Float16* wpsRZ[2] = { wrz0 + (size_t)(cb + rsub) * 1536,
                                 wrz0 + (size_t)(cb + 16 + rsub) * 1536 };
    const _Float16* wpsN[1] = { wn0 + (size_t)(nb + rsub) * 1536 };
    for (int t = 0; t < 512; ++t) {
      f4 aRZ[2] = { f4{0.f,0.f,0.f,0.f}, f4{0.f,0.f,0.f,0.f} };
      f4 aN[1] = { f4{0.f,0.f,0.f,0.f} };
      gemm_x(x, t, wpsRZ[0], wpsRZ[1], wpsN[0], aRZ, aN);   // no dependency
      // phase A: rz0(t)  (needs h0(t-1); t=0 -> zeros, skip)
      wait_ge(&cnt[1], 64ull * (u64)t);
      u64 hpre = pre_rz(h0f, cb);                           // gate prefetch under copy
      if (t >= 1) {
        copy_issue(h0bf + (size_t)((t - 1) & 1) * 65536, cpS[0], rankR, mR);
        crew_sync(&cc[0 * 16], (u64)mR * t);
        gemm_cp<2>(cpS[0], wpsRZ, 512, aRZ);
      }
      red_write<2>(red, aRZ);
      __syncthreads();
      reduce_rz(red, cb, brz0, hpre, rh0, z0f);
      signal(&cnt[0]);
      // phase B: n0(t)  (needs rh0(t); t=0 -> rh0==0, skip gemm)
      wait_ge(&cnt[0], 64ull * (u64)(t + 1));
      if (t >= 1) wait_ge(&cnt[3], 64ull * (u64)(t - 1));   // h0bf WAR
      u64 zpre = 0, hpre2 = 0;
      pre_n(z0f, h0f, nb, zpre, hpre2);
      if (t >= 1) {
        copy_issue(rh0, cpS[1], rankR, mR);
        crew_sync(&cc[1 * 16], (u64)mR * t);
        gemm_cp<1>(cpS[1], wpsN, 512, aN);
      }
      red_write<1>(red, aN);
      __syncthreads();
      reduce_n(red, nb, bn0, zpre, hpre2, h0f, h0bf + (size_t)(t & 1) * 65536);
      signal(&cnt[1]);
    }
  } else {
    // ---------- layer 1, step s = t-1 ----------
    const int b = bid - 64, cb = b * 32, nb = b * 16;
    const _Float16* wps3[3] = { wrz1 + (size_t)(cb + rsub) * 2048,
                                wrz1 + (size_t)(cb + 16 + rsub) * 2048,
                                wn1  + (size_t)(nb + rsub) * 2048 };
    for (int t = 1; t <= 512; ++t) {
      const int s = t - 1;
      f4 acc3[3] = { f4{0.f,0.f,0.f,0.f}, f4{0.f,0.f,0.f,0.f}, f4{0.f,0.f,0.f,0.f} };
      // phase A: rz1(s) — merged single crew barrier for h1- and h0-copies
      wait_ge(&cnt[3], 64ull * (u64)s);
      u64 hpre = pre_rz(h1f, cb);
      if (s >= 1)
        copy_issue(h1bf + (size_t)((s - 1) & 1) * 65536, cpS[2], rankR, mR);
      wait_ge(&cnt[1], 64ull * (u64)t);                     // h0(s) ready (drains h1 stores)
      copy_issue(h0bf + (size_t)((t - 1) & 1) * 65536, cpS[3], rankR, mR);
      crew_sync(&cc[3 * 16], (u64)mR * t);                  // one barrier covers both copies
      if (s >= 1) gemm_cp<2>(cpS[2], wps3, 1024, acc3);
      gemm_cp<3>(cpS[3], wps3, 0, acc3);
      red_write<2>(red, acc3);
      __syncthreads();
      reduce_rz(red, cb, brz1, hpre, rh1, z1f);
      signal(&cnt[2]);
      // phase B: n1(s) rh-part (s=0 -> rh1==0, skip gemm)
      wait_ge(&cnt[2], 64ull * (u64)t);
      u64 zpre = 0, hpre2 = 0;
      pre_n(z1f, h1f, nb, zpre, hpre2);
      if (s >= 1) {
        copy_issue(rh1, cpS[4], rankR, mR);
        crew_sync(&cc[4 * 16], (u64)mR * s);
        gemm_cp<1>(cpS[4], wps3 + 2, 1024, acc3 + 2);
      }
      red_write<1>(red, acc3 + 2);
      __syncthreads();
      reduce_n(red, nb, bn1, zpre, hpre2, h1f, h1bf + (size_t)(s & 1) * 65536);
      signal(&cnt[3]);
    }
  }
}

// ---------------- final fc: out[64,512] = h1 @ Wfc^T + bfc ----------------
__global__ __launch_bounds__(256) void fc_kernel(const float* __restrict__ h1f,
                                                 const float* __restrict__ wfc,
                                                 const float* __restrict__ bfc,
                                                 float* __restrict__ out) {
  const int bid = blockIdx.x;  // 64 blocks x 8 cols
#pragma unroll
  for (int rep = 0; rep < 2; ++rep) {
    int local = threadIdx.x + rep * 256;
    int b = local >> 3;
    int o = bid * 8 + (local & 7);
    const float4* hp = (const float4*)(h1f + (size_t)b * 1024);
    const float4* wp = (const float4*)(wfc + (size_t)o * 1024);
    float s = 0.f;
#pragma unroll 4
    for (int i2 = 0; i2 < 256; ++i2) {
      float4 hv = hp[i2], wv = wp[i2];
      s += hv.x * wv.x + hv.y * wv.y + hv.z * wv.z + hv.w * wv.w;
    }
    out[(size_t)b * 512 + o] = s + bfc[o];
  }
}

extern "C" void kernel_launch(void* const* d_in, const int* in_sizes, int n_in,
                              void* d_out, int out_size, void* d_ws, size_t ws_size,
                              hipStream_t stream) {
  const float* x    = (const float*)d_in[0];
  const float* Wrz0 = (const float*)d_in[1];
  const float* brz0 = (const float*)d_in[2];
  const float* Wn0  = (const float*)d_in[3];
  const float* bn0  = (const float*)d_in[4];
  const float* Wrz1 = (const float*)d_in[5];
  const float* brz1 = (const float*)d_in[6];
  const float* Wn1  = (const float*)d_in[7];
  const float* bn1  = (const float*)d_in[8];
  const float* Wfc  = (const float*)d_in[9];
  const float* bfc  = (const float*)d_in[10];
  float* out = (float*)d_out;
  char* ws = (char*)d_ws;

  _Float16* wrz0h = (_Float16*)(ws + OFF_WRZ0);
  _Float16* wn0h  = (_Float16*)(ws + OFF_WN0);
  _Float16* wrz1h = (_Float16*)(ws + OFF_WRZ1);
  _Float16* wn1h  = (_Float16*)(ws + OFF_WN1);
  _Float16* h0bf  = (_Float16*)(ws + OFF_H0BF);
  _Float16* h1bf  = (_Float16*)(ws + OFF_H1BF);
  _Float16* rh0   = (_Float16*)(ws + OFF_RH0);
  _Float16* rh1   = (_Float16*)(ws + OFF_RH1);
  float* h0f = (float*)(ws + OFF_H0F);
  float* h1f = (float*)(ws + OFF_H1F);
  float* z0f = (float*)(ws + OFF_Z0F);
  float* z1f = (float*)(ws + OFF_Z1F);
  u64* cnt = (u64*)(ws + OFF_CNT);
  unsigned* info = (unsigned*)(ws + OFF_INFO);
  u64* ccnt = (u64*)(ws + OFF_CCNT);
  char* cpbase = ws + OFF_CP;

  prep_kernel<<<2048, 256, 0, stream>>>(Wrz0, Wn0, Wrz1, Wn1,
                                        wrz0h, wn0h, wrz1h, wn1h,
                                        (unsigned*)(ws + OFF_H0BF));
  gru_main<<<128, 1024, 0, stream>>>(x, wrz0h, wn0h, wrz1h, wn1h,
                                     brz0, bn0, brz1, bn1,
                                     h0bf, h1bf, rh0, rh1,
                                     h0f, h1f, z0f, z1f,
                                     cnt, info, ccnt, cpbase);
  fc_kernel<<<64, 256, 0, stream>>>(h1f, Wfc, bfc, out);
}